// Round 7
// baseline (165.810 us; speedup 1.0000x reference)
//
#include <hip/hip_runtime.h>
#include <hip/hip_bf16.h>

typedef __attribute__((ext_vector_type(4))) float  f32x4;
typedef __attribute__((ext_vector_type(8))) short  s16x8;

#define D_MODEL 2048
#define SEQ     4096
#define BATCH   4
#define NATOMS  64
#define RANK    6
#define NLAYERS 16
#define NAR     (NATOMS*RANK)     /* 384 */
#define M_TOTAL (BATCH*SEQ)       /* 16384 */

#define WFSZ (128*64)   /* shorts per W buffer */

static __device__ __forceinline__ unsigned short f2bf(float x){
    union { float f; unsigned u; } v; v.f = x;
    unsigned r = (v.u + 0x7FFF + ((v.u >> 16) & 1)) >> 16;
    return (unsigned short)r;
}

static __device__ __forceinline__ void gload_lds16(const void* g, void* l) {
    __builtin_amdgcn_global_load_lds(
        (const __attribute__((address_space(1))) unsigned int*)g,
        (__attribute__((address_space(3))) unsigned int*)l, 16, 0, 0);
}

static __device__ __forceinline__ s16x8 cvt8(f32x4 lo, f32x4 hi) {
    union { s16x8 v; unsigned short s[8]; } u;
    u.s[0] = f2bf(lo.x); u.s[1] = f2bf(lo.y); u.s[2] = f2bf(lo.z); u.s[3] = f2bf(lo.w);
    u.s[4] = f2bf(hi.x); u.s[5] = f2bf(hi.y); u.s[6] = f2bf(hi.z); u.s[7] = f2bf(hi.w);
    return u.v;
}

// ---------------------------------------------------------------------------
// Prep: gather layer slice, cast to bf16, lay out K-contiguous.
// ---------------------------------------------------------------------------
__global__ void prep_kernel(const float* __restrict__ A,
                            const float* __restrict__ B,
                            const int*   __restrict__ layer_idx,
                            unsigned short* __restrict__ WbfT,
                            unsigned short* __restrict__ BbfT)
{
    const int l = layer_idx[0];
    int idx = blockIdx.x * 256 + threadIdx.x;
    const int total = NAR * D_MODEL;   // 786432
    if (idx < total) {
        int n = idx / D_MODEL, d = idx % D_MODEL;
        int a = n / RANK, r = n % RANK;
        float v = A[((size_t)(a*NLAYERS + l) * D_MODEL + d) * RANK + r];
        WbfT[idx] = f2bf(v);
    } else {
        idx -= total;
        int p = idx / NAR, n = idx % NAR;
        int a = n / RANK, r = n % RANK;
        float v = B[((size_t)(a*NLAYERS + l) * RANK + r) * D_MODEL + p];
        BbfT[idx] = f2bf(v);
    }
}

// ---------------------------------------------------------------------------
// GEMM1: P[m][n] = f2bf( scale[b, n/6] * sum_d hidden[m][d] * WbfT[n][d] )
//   M=16384, K=2048, N=384.  BM=64, BN=128, BK=64, 4 waves (2x2).
//   NO A-LDS: hidden loaded direct global->reg as MFMA A-fragments
//   (lane = 8 consecutive k of one m-row = 32B), ping-pong prefetched
//   1 iter ahead, cvt fp32->bf16 in-reg.  LDS = W only (dbuf, gload_lds,
//   XOR-preswizzled source).  Barrier: vmcnt(8) + raw s_barrier -> W(t+1)
//   drained, the 8 h(t+1) loads stay in flight across the barrier.
// ---------------------------------------------------------------------------
__global__ __launch_bounds__(256, 3) void gemm1(
    const float*          __restrict__ hidden,  // [16384][2048] fp32
    const float*          __restrict__ scales,  // [4][64]
    const unsigned short* __restrict__ WbfT,    // [384][2048] bf16
    unsigned short*       __restrict__ P)       // [16384][384] bf16
{
    __shared__ __align__(16) unsigned short Wf[2*WFSZ];  // 32 KB

    const int m0   = blockIdx.x * 64;
    const int n0   = blockIdx.y * 128;
    const int tid  = threadIdx.x;
    const int lane = tid & 63;
    const int wave = tid >> 6;
    const int wr   = wave >> 1, wc = wave & 1;

    // h-frag base: row = m0 + wr*32 + (lane&15), k-offset (lane>>4)*8.
    // frag(mi,kk) at + mi*16*D_MODEL + kk*32; advance by 64 per iter.
    const float* srcH =
        &hidden[(size_t)(m0 + wr * 32 + (lane & 15)) * D_MODEL + (lane >> 4) * 8];

    // W staging: 16 gload_lds of 1KB; wave w does insts i = w*4+j.
    // inst i, lane l -> LDS row r = i*8 + (l>>3), chunk c = l&7 (16B);
    // source pre-swizzled: LDS chunk c holds global chunk c^(r&7).
    const unsigned short* srcW[4];
    int ldsWoff[4];
    #pragma unroll
    for (int j = 0; j < 4; ++j) {
        int i = wave * 4 + j;
        int r = i * 8 + (lane >> 3);
        int c = (lane & 7) ^ (r & 7);
        srcW[j]    = &WbfT[(size_t)(n0 + r) * D_MODEL + c * 8];
        ldsWoff[j] = i * 512;  // shorts
    }

    f32x4 acc[2][4] = {};
    f32x4 ga[8], gb[8];   // ping-pong h prefetch; [f*2+half], f = mi*2+kk

    // ---- prologue: W(0) gloads, then h(0) loads ----
    #pragma unroll
    for (int j = 0; j < 4; ++j) { gload_lds16(srcW[j], &Wf[ldsWoff[j]]); srcW[j] += 64; }
    __builtin_amdgcn_sched_barrier(0);   // pin: W gloads before h loads
    #pragma unroll
    for (int f = 0; f < 4; ++f) {
        const float* p = srcH + (f >> 1) * (16 * D_MODEL) + (f & 1) * 32;
        ga[f * 2 + 0] = *reinterpret_cast<const f32x4*>(p);
        ga[f * 2 + 1] = *reinterpret_cast<const f32x4*>(p + 4);
    }
    srcH += 64;
    asm volatile("s_waitcnt vmcnt(8)" ::: "memory");  // W(0) done; h(0) in flight
    __builtin_amdgcn_s_barrier();

    // ---- main loop ----
    auto body = [&](int t, f32x4 (&gC)[8], f32x4 (&gN)[8]) {
        const int buf = t & 1;
        // 1. issue W(t+1) into buf^1
        if (t < 31) {
            #pragma unroll
            for (int j = 0; j < 4; ++j) {
                gload_lds16(srcW[j], &Wf[(buf ^ 1) * WFSZ + ldsWoff[j]]);
                srcW[j] += 64;
            }
        }
        __builtin_amdgcn_sched_barrier(0);   // pin: W before h (vmcnt arithmetic)
        // 2. issue h(t+1)
        if (t < 31) {
            #pragma unroll
            for (int f = 0; f < 4; ++f) {
                const float* p = srcH + (f >> 1) * (16 * D_MODEL) + (f & 1) * 32;
                gN[f * 2 + 0] = *reinterpret_cast<const f32x4*>(p);
                gN[f * 2 + 1] = *reinterpret_cast<const f32x4*>(p + 4);
            }
            srcH += 64;
        }
        // 3. cvt h(t) in-reg, compute with W from LDS
        s16x8 hfr[2][2];
        #pragma unroll
        for (int f = 0; f < 4; ++f)
            hfr[f >> 1][f & 1] = cvt8(gC[f * 2], gC[f * 2 + 1]);
        const unsigned short* Wr = &Wf[buf * WFSZ];
        #pragma unroll
        for (int kk = 0; kk < 2; ++kk) {
            const int kch = kk * 4 + (lane >> 4);   // 16B-chunk index 0..7
            s16x8 bfr[4];
            #pragma unroll
            for (int ni = 0; ni < 4; ++ni) {
                int br = wc * 64 + ni * 16 + (lane & 15);
                bfr[ni] = *reinterpret_cast<const s16x8*>(
                    &Wr[br * 64 + ((kch ^ (br & 7)) << 3)]);
            }
            #pragma unroll
            for (int mi = 0; mi < 2; ++mi)
                #pragma unroll
                for (int ni = 0; ni < 4; ++ni)
                    acc[mi][ni] = __builtin_amdgcn_mfma_f32_16x16x32_bf16(
                        hfr[mi][kk], bfr[ni], acc[mi][ni], 0, 0, 0);
        }
        // 4. barrier: drain W(t+1) [4 oldest], keep h(t+1) [8 newest] in flight
        if (t < 31) {
            asm volatile("s_waitcnt vmcnt(8)" ::: "memory");
            __builtin_amdgcn_s_barrier();
        }
    };
    for (int tt = 0; tt < 32; tt += 2) {
        body(tt,     ga, gb);
        body(tt + 1, gb, ga);
    }

    // ---- epilogue: scale by atom_scales[b, n/6], store bf16 ----
    const int b    = m0 >> 12;
    const int row0 = m0 + wr * 32;
    const int col0 = n0 + wc * 64;
    #pragma unroll
    for (int ni = 0; ni < 4; ++ni) {
        int col  = col0 + ni * 16 + (lane & 15);
        float sc = scales[b * NATOMS + col / RANK];
        #pragma unroll
        for (int mi = 0; mi < 2; ++mi) {
            #pragma unroll
            for (int r = 0; r < 4; ++r) {
                int row = row0 + mi * 16 + (lane >> 4) * 4 + r;
                P[(size_t)row * NAR + col] = f2bf(acc[mi][ni][r] * sc);
            }
        }
    }
}

// ---------------------------------------------------------------------------
// GEMM2: out[m][p] = sum_n P[m][n] * BbfT[p][n]   (at HBM roofline)
// ---------------------------------------------------------------------------
__global__ __launch_bounds__(256, 2) void gemm2(
    const unsigned short* __restrict__ P,     // [16384][384] bf16
    const unsigned short* __restrict__ BbfT,  // [2048][384] bf16
    float*                __restrict__ out)   // [16384][2048] fp32
{
    __shared__ unsigned short Pt[128][72];
    __shared__ unsigned short Bt[128][72];

    const int m0   = blockIdx.x * 128;
    const int p0   = blockIdx.y * 128;
    const int tid  = threadIdx.x;
    const int lane = tid & 63;
    const int wave = tid >> 6;
    const int wr   = wave >> 1, wc = wave & 1;

    f32x4 acc[4][4] = {};

    for (int k0 = 0; k0 < NAR; k0 += 64) {
        #pragma unroll
        for (int pass = 0; pass < 4; ++pass) {
            int c   = tid + pass * 256;
            int row = c >> 3, c8 = c & 7;
            s16x8 v = *reinterpret_cast<const s16x8*>(
                &P[(size_t)(m0 + row) * NAR + k0 + c8 * 8]);
            *reinterpret_cast<s16x8*>(&Pt[row][c8 * 8]) = v;
        }
        #pragma unroll
        for (int pass = 0; pass < 4; ++pass) {
            int c   = tid + pass * 256;
            int row = c >> 3, c8 = c & 7;
            s16x8 v = *reinterpret_cast<const s16x8*>(
                &BbfT[(size_t)(p0 + row) * NAR + k0 + c8 * 8]);
            *reinterpret_cast<s16x8*>(&Bt[row][c8 * 8]) = v;
        }
        __syncthreads();

        #pragma unroll
        for (int kk = 0; kk < 64; kk += 32) {
            const int krow = kk + (lane >> 4) * 8;
            s16x8 a_frag[4], b_frag[4];
            #pragma unroll
            for (int mi = 0; mi < 4; ++mi)
                a_frag[mi] = *reinterpret_cast<const s16x8*>(
                    &Pt[wr * 64 + mi * 16 + (lane & 15)][krow]);
            #pragma unroll
            for (int ni = 0; ni < 4; ++ni)
                b_frag[ni] = *reinterpret_cast<const s16x8*>(
                    &Bt[wc * 64 + ni * 16 + (lane & 15)][krow]);
            #pragma unroll
            for (int mi = 0; mi < 4; ++mi)
                #pragma unroll
                for (int ni = 0; ni < 4; ++ni)
                    acc[mi][ni] = __builtin_amdgcn_mfma_f32_16x16x32_bf16(
                        a_frag[mi], b_frag[ni], acc[mi][ni], 0, 0, 0);
        }
        __syncthreads();
    }

    const int row0 = m0 + wr * 64;
    const int col0 = p0 + wc * 64;
    #pragma unroll
    for (int mi = 0; mi < 4; ++mi) {
        #pragma unroll
        for (int ni = 0; ni < 4; ++ni) {
            int col = col0 + ni * 16 + (lane & 15);
            #pragma unroll
            for (int r = 0; r < 4; ++r) {
                int row = row0 + mi * 16 + (lane >> 4) * 4 + r;
                out[(size_t)row * D_MODEL + col] = acc[mi][ni][r];
            }
        }
    }
}

extern "C" void kernel_launch(void* const* d_in, const int* in_sizes, int n_in,
                              void* d_out, int out_size, void* d_ws, size_t ws_size,
                              hipStream_t stream)
{
    const float* hidden    = (const float*)d_in[0];
    const float* scales    = (const float*)d_in[1];
    const float* A         = (const float*)d_in[2];
    const float* B         = (const float*)d_in[3];
    const int*   layer_idx = (const int*)d_in[4];
    float* out = (float*)d_out;

    unsigned short* WbfT = (unsigned short*)d_ws;            // [384][2048]
    unsigned short* BbfT = WbfT + (size_t)NAR * D_MODEL;     // [2048][384]
    unsigned short* P    = BbfT + (size_t)D_MODEL * NAR;     // [16384][384]

    prep_kernel<<<(2 * NAR * D_MODEL) / 256, 256, 0, stream>>>(A, B, layer_idx, WbfT, BbfT);
    gemm1<<<dim3(M_TOTAL / 64, NAR / 128), 256, 0, stream>>>(hidden, scales, WbfT, P);
    gemm2<<<dim3(M_TOTAL / 128, D_MODEL / 128), 256, 0, stream>>>(P, BbfT, out);
}

// Round 8
// 93.972 us; speedup vs baseline: 1.7645x; 1.7645x over previous
//
#include <hip/hip_runtime.h>
#include <hip/hip_bf16.h>

typedef __attribute__((ext_vector_type(4))) float  f32x4;
typedef __attribute__((ext_vector_type(8))) short  s16x8;

#define D_MODEL 2048
#define SEQ     4096
#define BATCH   4
#define NATOMS  64
#define RANK    6
#define NLAYERS 16
#define NAR     (NATOMS*RANK)     /* 384 */
#define M_TOTAL (BATCH*SEQ)       /* 16384 */

#define ASZ  (64*72)    /* shorts: A buffer (+8 pad) */
#define WSZ  (384*64)   /* shorts: W buffer (linear, gload_lds) */
#define BSZ  (64*392)   /* shorts: B buffer (+8 pad) */
#define PSTR 392        /* P_lds row stride in shorts */

static __device__ __forceinline__ unsigned short f2bf(float x){
    union { float f; unsigned u; } v; v.f = x;
    unsigned r = (v.u + 0x7FFF + ((v.u >> 16) & 1)) >> 16;
    return (unsigned short)r;
}

static __device__ __forceinline__ void gload_lds16(const void* g, void* l) {
    __builtin_amdgcn_global_load_lds(
        (const __attribute__((address_space(1))) unsigned int*)g,
        (__attribute__((address_space(3))) unsigned int*)l, 16, 0, 0);
}

static __device__ __forceinline__ s16x8 cvt8(f32x4 lo, f32x4 hi) {
    union { s16x8 v; unsigned short s[8]; } u;
    u.s[0] = f2bf(lo.x); u.s[1] = f2bf(lo.y); u.s[2] = f2bf(lo.z); u.s[3] = f2bf(lo.w);
    u.s[4] = f2bf(hi.x); u.s[5] = f2bf(hi.y); u.s[6] = f2bf(hi.z); u.s[7] = f2bf(hi.w);
    return u.v;
}

// ---------------------------------------------------------------------------
// Prep: gather layer slice, cast to bf16, lay out K-contiguous.
//   WbfT[n][d]  (n = a*6+r)   from A[a, l, d, r]
//   BbfT[p][n]                from B[a, l, r, p]
// ---------------------------------------------------------------------------
__global__ void prep_kernel(const float* __restrict__ A,
                            const float* __restrict__ B,
                            const int*   __restrict__ layer_idx,
                            unsigned short* __restrict__ WbfT,
                            unsigned short* __restrict__ BbfT)
{
    const int l = layer_idx[0];
    int idx = blockIdx.x * 256 + threadIdx.x;
    const int total = NAR * D_MODEL;   // 786432
    if (idx < total) {
        int n = idx / D_MODEL, d = idx % D_MODEL;
        int a = n / RANK, r = n % RANK;
        float v = A[((size_t)(a*NLAYERS + l) * D_MODEL + d) * RANK + r];
        WbfT[idx] = f2bf(v);
    } else {
        idx -= total;
        int p = idx / NAR, n = idx % NAR;
        int a = n / RANK, r = n % RANK;
        float v = B[((size_t)(a*NLAYERS + l) * RANK + r) * D_MODEL + p];
        BbfT[idx] = f2bf(v);
    }
}

// ---------------------------------------------------------------------------
// Fused LoRA: per block (256 blocks = 1/CU, 512 threads = 8 waves):
//   Phase 1: P[64][384] = scale * (hidden[64 rows] @ W^T), acc in regs.
//            hidden read ONCE (no 3x panel multiplicity).  W dbuf via
//            gload_lds (XOR-preswizzled source), A reg-staged, counted
//            vmcnt(2) barriers (A prefetch 2-deep stays in flight).
//   Phase 2: out[64][2048] = P @ B^T.  P-frags in regs (constant across
//            p-tiles); B (L2-resident) reg-staged per 64-col tile, dbuf.
// ---------------------------------------------------------------------------
__global__ __launch_bounds__(512, 1) void fused_lora(
    const float*          __restrict__ hidden,  // [16384][2048] fp32
    const float*          __restrict__ scales,  // [4][64]
    const unsigned short* __restrict__ WbfT,    // [384][2048] bf16
    const unsigned short* __restrict__ BbfT,    // [2048][384] bf16
    float*                __restrict__ out)     // [16384][2048] fp32
{
    __shared__ __align__(16) char smem[150528];
    unsigned short* Af = (unsigned short*)smem;            // 2*ASZ  (18432 B)
    unsigned short* Wf = (unsigned short*)(smem + 18432);  // 2*WSZ  (98304 B)
    unsigned short* Pl = (unsigned short*)smem;            // 64*392 (50176 B)
    unsigned short* Bt = (unsigned short*)(smem + 50176);  // 2*BSZ  (100352 B)

    const int m0   = blockIdx.x * 64;
    const int tid  = threadIdx.x;
    const int lane = tid & 63;
    const int w    = tid >> 6;          // 0..7
    const int wr   = w >> 2, wc = w & 3;   // phase1: rows wr*32, cols wc*96

    // ---- phase 1 setup ----
    // A staging: thread -> row rowA, floats [c8A*8, c8A*8+8)
    const int rowA = tid >> 3;          // 0..63
    const int c8A  = tid & 7;           // 0..7
    const float* srcA = hidden + (size_t)(m0 + rowA) * D_MODEL + c8A * 8;

    // W staging: 48 gload_lds of 1KB; wave w does insts i = w*6+j.
    // inst i, lane l -> LDS row r = i*8+(l>>3), chunk c = l&7 (16B);
    // source pre-swizzled: LDS chunk c holds global chunk c^(r&7).
    const unsigned short* srcW[6];
    int ldsW[6];
    #pragma unroll
    for (int j = 0; j < 6; ++j) {
        int i = w * 6 + j;
        int r = i * 8 + (lane >> 3);
        int c = (lane & 7) ^ (r & 7);
        srcW[j] = WbfT + (size_t)r * D_MODEL + c * 8;
        ldsW[j] = i * 512;   // shorts
    }

    f32x4 acc[2][6] = {};
    f32x4 ga[2], gb[2];

    // ---- phase 1 prologue ----
    ga[0] = *reinterpret_cast<const f32x4*>(srcA);
    ga[1] = *reinterpret_cast<const f32x4*>(srcA + 4);
    srcA += 64;
    {
        s16x8 s = cvt8(ga[0], ga[1]);
        *reinterpret_cast<s16x8*>(&Af[rowA * 72 + c8A * 8]) = s;
    }
    #pragma unroll
    for (int j = 0; j < 6; ++j) { gload_lds16(srcW[j], &Wf[ldsW[j]]); srcW[j] += 64; }
    __builtin_amdgcn_sched_barrier(0);
    gb[0] = *reinterpret_cast<const f32x4*>(srcA);          // A(1)
    gb[1] = *reinterpret_cast<const f32x4*>(srcA + 4);
    srcA += 64;
    asm volatile("s_waitcnt vmcnt(2) lgkmcnt(0)" ::: "memory");  // W(0) done, A(1) in flight
    __builtin_amdgcn_s_barrier();

    // ---- phase 1 main loop ----
    auto body = [&](int t, f32x4 (&gI)[2], f32x4 (&gC)[2]) {
        const int buf = t & 1;
        if (t < 31) {
            #pragma unroll
            for (int j = 0; j < 6; ++j) {
                gload_lds16(srcW[j], &Wf[(buf ^ 1) * WSZ + ldsW[j]]);
                srcW[j] += 64;
            }
        }
        __builtin_amdgcn_sched_barrier(0);   // pin: W gloads before A loads
        if (t < 30) {
            gI[0] = *reinterpret_cast<const f32x4*>(srcA);
            gI[1] = *reinterpret_cast<const f32x4*>(srcA + 4);
            srcA += 64;
        }
        const unsigned short* Ar = &Af[buf * ASZ];
        const unsigned short* Wr = &Wf[buf * WSZ];
        #pragma unroll
        for (int kk = 0; kk < 2; ++kk) {
            const int kch = kk * 4 + (lane >> 4);
            s16x8 bfr[6], afr[2];
            #pragma unroll
            for (int ni = 0; ni < 6; ++ni) {
                int br = wc * 96 + ni * 16 + (lane & 15);
                bfr[ni] = *reinterpret_cast<const s16x8*>(
                    &Wr[br * 64 + ((kch ^ (br & 7)) << 3)]);
            }
            #pragma unroll
            for (int mi = 0; mi < 2; ++mi) {
                int ar = wr * 32 + mi * 16 + (lane & 15);
                afr[mi] = *reinterpret_cast<const s16x8*>(
                    &Ar[ar * 72 + kk * 32 + (lane >> 4) * 8]);
            }
            #pragma unroll
            for (int mi = 0; mi < 2; ++mi)
                #pragma unroll
                for (int ni = 0; ni < 6; ++ni)
                    acc[mi][ni] = __builtin_amdgcn_mfma_f32_16x16x32_bf16(
                        afr[mi], bfr[ni], acc[mi][ni], 0, 0, 0);
        }
        if (t < 31) {
            s16x8 s = cvt8(gC[0], gC[1]);
            *reinterpret_cast<s16x8*>(&Af[(buf ^ 1) * ASZ + rowA * 72 + c8A * 8]) = s;
            if (t == 30) asm volatile("s_waitcnt vmcnt(0) lgkmcnt(0)" ::: "memory");
            else         asm volatile("s_waitcnt vmcnt(2) lgkmcnt(0)" ::: "memory");
            __builtin_amdgcn_s_barrier();
        }
    };
    for (int tt = 0; tt < 32; tt += 2) {
        body(tt,     ga, gb);
        body(tt + 1, gb, ga);
    }
    __syncthreads();   // phase-1 LDS reads complete; safe to overwrite with P

    // ---- transition: scale + cvt acc -> P_lds ----
    const int b = m0 >> 12;
    #pragma unroll
    for (int ni = 0; ni < 6; ++ni) {
        int col  = wc * 96 + ni * 16 + (lane & 15);
        float sc = scales[b * NATOMS + col / RANK];
        #pragma unroll
        for (int mi = 0; mi < 2; ++mi) {
            #pragma unroll
            for (int r = 0; r < 4; ++r) {
                int row = wr * 32 + mi * 16 + (lane >> 4) * 4 + r;
                Pl[row * PSTR + col] = f2bf(acc[mi][ni][r] * sc);
            }
        }
    }
    __syncthreads();

    // ---- phase 2 setup ----
    const int wr2 = w >> 2, wp = w & 3;   // out rows wr2*32, cols (pt*64 + wp*16)
    // B staging map: 3072 granules of 16B -> (row, chunk); thread owns 6.
    const unsigned short* srcB[6];
    int dstB[6];
    #pragma unroll
    for (int j = 0; j < 6; ++j) {
        int g  = j * 512 + tid;
        int rB = g / 48, cB = g % 48;
        srcB[j] = BbfT + (size_t)rB * NAR + cB * 8;
        dstB[j] = rB * PSTR + cB * 8;
    }
    // P fragments -> regs once (constant across p-tiles)
    s16x8 pf[2][12];
    #pragma unroll
    for (int mi = 0; mi < 2; ++mi)
        #pragma unroll
        for (int ks = 0; ks < 12; ++ks)
            pf[mi][ks] = *reinterpret_cast<const s16x8*>(
                &Pl[(wr2 * 32 + mi * 16 + (lane & 15)) * PSTR + (ks * 4 + (lane >> 4)) * 8]);

    // phase 2 prologue: stage B(0)
    s16x8 gB[6];
    #pragma unroll
    for (int j = 0; j < 6; ++j) gB[j] = *reinterpret_cast<const s16x8*>(srcB[j]);
    #pragma unroll
    for (int j = 0; j < 6; ++j) *reinterpret_cast<s16x8*>(&Bt[dstB[j]]) = gB[j];
    asm volatile("s_waitcnt lgkmcnt(0)" ::: "memory");
    __builtin_amdgcn_s_barrier();

    // ---- phase 2 main loop: 32 p-tiles of 64 cols ----
    for (int pt = 0; pt < 32; ++pt) {
        const int buf = pt & 1;
        if (pt < 31) {
            #pragma unroll
            for (int j = 0; j < 6; ++j)
                gB[j] = *reinterpret_cast<const s16x8*>(srcB[j] + (size_t)(pt + 1) * 64 * NAR);
        }
        f32x4 a2[2] = {};
        #pragma unroll
        for (int ks = 0; ks < 12; ++ks) {
            s16x8 bfr = *reinterpret_cast<const s16x8*>(
                &Bt[buf * BSZ + (wp * 16 + (lane & 15)) * PSTR + (ks * 4 + (lane >> 4)) * 8]);
            #pragma unroll
            for (int mi = 0; mi < 2; ++mi)
                a2[mi] = __builtin_amdgcn_mfma_f32_16x16x32_bf16(
                    pf[mi][ks], bfr, a2[mi], 0, 0, 0);
        }
        #pragma unroll
        for (int mi = 0; mi < 2; ++mi) {
            #pragma unroll
            for (int r = 0; r < 4; ++r) {
                int row = m0 + wr2 * 32 + mi * 16 + (lane >> 4) * 4 + r;
                int col = pt * 64 + wp * 16 + (lane & 15);
                out[(size_t)row * D_MODEL + col] = a2[mi][r];
            }
        }
        if (pt < 31) {
            #pragma unroll
            for (int j = 0; j < 6; ++j)
                *reinterpret_cast<s16x8*>(&Bt[(buf ^ 1) * BSZ + dstB[j]]) = gB[j];
            asm volatile("s_waitcnt lgkmcnt(0)" ::: "memory");
            __builtin_amdgcn_s_barrier();
        }
    }
}

extern "C" void kernel_launch(void* const* d_in, const int* in_sizes, int n_in,
                              void* d_out, int out_size, void* d_ws, size_t ws_size,
                              hipStream_t stream)
{
    const float* hidden    = (const float*)d_in[0];
    const float* scales    = (const float*)d_in[1];
    const float* A         = (const float*)d_in[2];
    const float* B         = (const float*)d_in[3];
    const int*   layer_idx = (const int*)d_in[4];
    float* out = (float*)d_out;

    unsigned short* WbfT = (unsigned short*)d_ws;            // [384][2048]
    unsigned short* BbfT = WbfT + (size_t)NAR * D_MODEL;     // [2048][384]

    prep_kernel<<<(2 * NAR * D_MODEL) / 256, 256, 0, stream>>>(A, B, layer_idx, WbfT, BbfT);
    fused_lora<<<M_TOTAL / 64, 512, 0, stream>>>(hidden, scales, WbfT, BbfT, out);
}